// Round 3
// baseline (1828.304 us; speedup 1.0000x reference)
//
#include <hip/hip_runtime.h>
#include <stdint.h>

typedef unsigned short u16;
typedef unsigned int   u32;
typedef __attribute__((ext_vector_type(4)))  short s4v;
typedef __attribute__((ext_vector_type(8)))  short s8v;
typedef __attribute__((ext_vector_type(16))) float f16v;
typedef __attribute__((ext_vector_type(2)))  float f2v;
typedef __attribute__((ext_vector_type(4)))  float f4v;

#define JJ 17
#define CC 128
#define BB 7
#define ROWS (BB*JJ)     // 119
#define PP 128
#define XP 132           // u16 pitch: 264B rows, 8B-aligned; b64 reads at bank floor
#define NLAYERS 5
#define NT 512

#define XBUF_BYTES (PP*XP*4)             // 67584: xh/xl u16 pair; h1 f32 alias; wf32 alias
#define WLO_OFF    XBUF_BYTES
#define WLO_BYTES  (2*PP*XP*2)           // 67584
#define ADJS_OFF   (WLO_OFF + WLO_BYTES) // 135168
#define DIAG_OFF   (ADJS_OFF + 1216)
#define BIAS_OFF   (DIAG_OFF + 512)
#define LDS_BYTES  (BIAS_OFF + 512)      // 137408 -> 1 block/CU

__device__ __forceinline__ u16 f2bf(float f) {
  u32 u = __float_as_uint(f);
  u += 0x7FFFu + ((u >> 16) & 1u);   // RNE
  return (u16)(u >> 16);
}
__device__ __forceinline__ float bf2f(u16 h) {
  return __uint_as_float(((u32)h) << 16);
}
__device__ __forceinline__ s8v cmb(s4v a, s4v b) {
  s8v r;
  r[0]=a[0]; r[1]=a[1]; r[2]=a[2]; r[3]=a[3];
  r[4]=b[0]; r[5]=b[1]; r[6]=b[2]; r[7]=b[3];
  return r;
}
__device__ __forceinline__ float wred(float v) {
  #pragma unroll
  for (int m = 32; m >= 1; m >>= 1) v += __shfl_xor(v, m, 64);
  return v;
}

__global__ void __launch_bounds__(NT, 2)
gconv_fused(const float* __restrict__ x, const float* __restrict__ x0,
            const float* __restrict__ adj, const float* __restrict__ W0,
            const float* __restrict__ W1, const float* __restrict__ bvec,
            const float* __restrict__ gamma, const float* __restrict__ beta,
            float* __restrict__ out, int totRows)
{
  extern __shared__ char smem[];
  u16*   xh    = (u16*)smem;                   // [PP][XP]
  u16*   xl    = xh + PP*XP;
  float* h1    = (float*)smem;                 // alias, [PP][XP] f32
  float* wf32  = (float*)smem;                 // alias, flat [16384] f32
  u16*   wlo   = (u16*)(smem + WLO_OFF);       // [2][PP][XP] (n-major, k-pitched)
  float* adjs  = (float*)(smem + ADJS_OFF);    // 0.8*adj, diag zeroed
  float* diag8 = (float*)(smem + DIAG_OFF);
  float* biasl = (float*)(smem + BIAS_OFF);

  const int tid  = threadIdx.x;
  const int lane = tid & 63;
  const int wid  = tid >> 6;        // 0..7
  const int wm   = wid >> 2;        // 0..1  (M half: rows wm*64..)
  const int wn   = wid & 3;         // 0..3  (N tile)
  const int g    = lane >> 5;
  const int nl   = lane & 31;
  const int ccol = wn*32 + nl;
  const int grow0 = blockIdx.x * ROWS;

  // ---- W prep: f32 bounce via LDS; whi -> regs, wlo -> LDS (resident all layers)
  s8v whi[2][8];
  #pragma unroll
  for (int w01 = 0; w01 < 2; ++w01) {
    const float* Wp = w01 ? W1 : W0;
    if (w01) __syncthreads();
    #pragma unroll
    for (int i = 0; i < 32; ++i) wf32[tid + i*NT] = Wp[tid + i*NT];
    __syncthreads();
    #pragma unroll
    for (int ks = 0; ks < 8; ++ks) {
      s8v v;
      #pragma unroll
      for (int e = 0; e < 8; ++e)
        v[e] = (short)f2bf(wf32[(ks*16 + 8*g + e)*CC + ccol]);
      whi[w01][ks] = v;
    }
    #pragma unroll
    for (int i = 0; i < 32; ++i) {
      int el = tid + i*NT;
      int k = el >> 7, n = el & 127;
      float v = wf32[el];
      u16 h = f2bf(v);
      wlo[(w01*PP + n)*XP + k] = f2bf(v - bf2f(h));
    }
  }
  __syncthreads();   // wf32 (xbuf) free

  // ---- x -> xh/xl (float4), pad rows zero
  #pragma unroll
  for (int i = 0; i < 8; ++i) {
    int el4 = tid + i*NT;            // 4096 float4
    int r = el4 >> 5, c4 = (el4 & 31) << 2;
    f4v v; v[0]=0.f; v[1]=0.f; v[2]=0.f; v[3]=0.f;
    if (r < ROWS && (grow0 + r) < totRows)
      v = *(const f4v*)&x[(size_t)(grow0 + r)*CC + c4];
    s4v sh, sl;
    #pragma unroll
    for (int e = 0; e < 4; ++e) {
      u16 hh = f2bf(v[e]);
      sh[e] = (short)hh;
      sl[e] = (short)f2bf(v[e] - bf2f(hh));
    }
    *(s4v*)&xh[r*XP + c4] = sh;
    *(s4v*)&xl[r*XP + c4] = sl;
  }
  if (tid < JJ*JJ) {
    int j = tid / JJ, k = tid - j*JJ;
    adjs[tid] = (j == k) ? 0.f : 0.8f * adj[tid];
  }
  if (tid < PP) {
    int j = tid % JJ;
    diag8[tid] = (tid < ROWS) ? 0.8f * adj[j*JJ + j] : 0.f;
    biasl[tid] = bvec[tid];
  }
  __syncthreads();

  // ================= layer loop =================
  #pragma unroll 1
  for (int layer = 0; layer < NLAYERS; ++layer) {
    f16v acc0[2], acc1[2];
    #pragma unroll
    for (int mt = 0; mt < 2; ++mt)
      #pragma unroll
      for (int i = 0; i < 16; ++i) { acc0[mt][i] = 0.f; acc1[mt][i] = 0.f; }

    // ---- GEMM: LDS + regs only, no barriers
    #pragma unroll
    for (int ks = 0; ks < 8; ++ks) {
      const int bb0 = ccol*XP + ks*16 + 8*g;
      s8v bl0 = cmb(*(const s4v*)&wlo[bb0], *(const s4v*)&wlo[bb0+4]);
      s8v bl1 = cmb(*(const s4v*)&wlo[PP*XP + bb0], *(const s4v*)&wlo[PP*XP + bb0+4]);
      #pragma unroll
      for (int mt = 0; mt < 2; ++mt) {
        const int xb = (wm*64 + mt*32 + nl)*XP + ks*16 + 8*g;
        s8v ah = cmb(*(const s4v*)&xh[xb], *(const s4v*)&xh[xb+4]);
        s8v al = cmb(*(const s4v*)&xl[xb], *(const s4v*)&xl[xb+4]);
        acc0[mt] = __builtin_amdgcn_mfma_f32_32x32x16_bf16(ah, whi[0][ks], acc0[mt], 0, 0, 0);
        acc0[mt] = __builtin_amdgcn_mfma_f32_32x32x16_bf16(al, whi[0][ks], acc0[mt], 0, 0, 0);
        acc0[mt] = __builtin_amdgcn_mfma_f32_32x32x16_bf16(ah, bl0,        acc0[mt], 0, 0, 0);
        acc1[mt] = __builtin_amdgcn_mfma_f32_32x32x16_bf16(ah, whi[1][ks], acc1[mt], 0, 0, 0);
        acc1[mt] = __builtin_amdgcn_mfma_f32_32x32x16_bf16(al, whi[1][ks], acc1[mt], 0, 0, 0);
        acc1[mt] = __builtin_amdgcn_mfma_f32_32x32x16_bf16(ah, bl1,        acc1[mt], 0, 0, 0);
      }
    }
    __syncthreads();               // xh/xl reads done (h1 aliases them)

    // ---- epilogue: acc1 (X@W1) -> h1
    #pragma unroll
    for (int mt = 0; mt < 2; ++mt)
      #pragma unroll
      for (int q = 0; q < 16; ++q) {
        int row = wm*64 + mt*32 + (q&3) + 8*(q>>2) + 4*g;
        h1[row*XP + ccol] = acc1[mt][q];
      }
    __syncthreads();

    // ---- joint mix in place (wave wid = batch elem)
    if (wid < BB) {
      const int rb = wid * JJ;
      f2v h[JJ];
      #pragma unroll
      for (int k = 0; k < JJ; ++k)
        h[k] = *(const f2v*)&h1[(rb+k)*XP + 2*lane];
      #pragma unroll 1
      for (int j = 0; j < JJ; ++j) {
        f2v m; m.x = 0.f; m.y = 0.f;
        #pragma unroll
        for (int k = 0; k < JJ; ++k) {
          float a = adjs[j*JJ + k];
          m.x += a * h[k].x; m.y += a * h[k].y;
        }
        *(f2v*)&h1[(rb+j)*XP + 2*lane] = m;
      }
    }
    __syncthreads();

    // ---- combine A: gather into regs (x0 lazy from global; L2-resident after L0)
    float tmp[2][16];
    #pragma unroll
    for (int mt = 0; mt < 2; ++mt)
      #pragma unroll
      for (int q = 0; q < 16; ++q) {
        int row = wm*64 + mt*32 + (q&3) + 8*(q>>2) + 4*g;
        int grow = grow0 + row;
        float x0v = (row < ROWS && grow < totRows) ? x0[(size_t)grow*CC + ccol] : 0.f;
        tmp[mt][q] = 0.2f*x0v + diag8[row]*acc0[mt][q] + h1[row*XP + ccol] + biasl[ccol];
      }
    __syncthreads();               // h1 reads done before xh/xl overwrite

    // ---- combine B: write new x split
    #pragma unroll
    for (int mt = 0; mt < 2; ++mt)
      #pragma unroll
      for (int q = 0; q < 16; ++q) {
        int row = wm*64 + mt*32 + (q&3) + 8*(q>>2) + 4*g;
        u16 hh = f2bf(tmp[mt][q]);
        xh[row*XP + ccol] = hh;
        xl[row*XP + ccol] = f2bf(tmp[mt][q] - bf2f(hh));
      }
    __syncthreads();
  }

  // ---- LayerNorm + store
  float ga = gamma[lane], g2 = gamma[64+lane];
  float ba = beta[lane],  b2 = beta[64+lane];
  #pragma unroll 1
  for (int i = 0; i < 16; ++i) {
    int r = wid + 8*i;             // 0..127, wave-uniform
    if (r >= ROWS) continue;
    int grow = grow0 + r;
    if (grow >= totRows) continue;
    int xb = r*XP;
    float xa = bf2f(xh[xb+lane])    + bf2f(xl[xb+lane]);
    float xc = bf2f(xh[xb+64+lane]) + bf2f(xl[xb+64+lane]);
    float mu = wred(xa + xc) * (1.f/128.f);
    float da = xa - mu, dc = xc - mu;
    float vs = wred(da*da + dc*dc) * (1.f/128.f);
    float rs = rsqrtf(vs + 1e-10f);
    size_t ob = (size_t)grow*CC;
    out[ob + lane]      = da*rs*ga + ba;
    out[ob + 64 + lane] = dc*rs*g2 + b2;
  }
}

extern "C" void kernel_launch(void* const* d_in, const int* in_sizes, int n_in,
                              void* d_out, int out_size, void* d_ws, size_t ws_size,
                              hipStream_t stream) {
  const float* x   = (const float*)d_in[0];
  const float* x0  = (const float*)d_in[1];
  const float* adj = (const float*)d_in[2];
  const float* W0  = (const float*)d_in[3];
  const float* W1  = (const float*)d_in[4];
  const float* bv  = (const float*)d_in[5];
  const float* ga  = (const float*)d_in[6];
  const float* be  = (const float*)d_in[7];
  int totRows = in_sizes[0] / CC;
  int nBatch  = totRows / JJ;
  int grid    = (nBatch + BB - 1) / BB;
  hipFuncSetAttribute((const void*)gconv_fused,
                      hipFuncAttributeMaxDynamicSharedMemorySize, LDS_BYTES);
  gconv_fused<<<dim3(grid), dim3(NT), LDS_BYTES, stream>>>(
      x, x0, adj, W0, W1, bv, ga, be, (float*)d_out, totRows);
}

// Round 4
// 769.243 us; speedup vs baseline: 2.3768x; 2.3768x over previous
//
#include <hip/hip_runtime.h>
#include <stdint.h>

typedef unsigned short u16;
typedef unsigned int   u32;
typedef __attribute__((ext_vector_type(4)))  short s4v;
typedef __attribute__((ext_vector_type(8)))  short s8v;
typedef __attribute__((ext_vector_type(16))) float f16v;
typedef __attribute__((ext_vector_type(2)))  float f2v;
typedef __attribute__((ext_vector_type(4)))  float f4v;

#define JJ 17
#define CC 128
#define BB 7
#define ROWS (BB*JJ)     // 119
#define PP 128
#define XP 132           // u16 pitch: 264B rows; b64 lane stride 66dw = 2-way bank (free)
#define NLAYERS 5
#define NT 512

#define XBUF_BYTES (PP*XP*4)             // 67584: xh/xl u16 pair; h1 f32 alias; wf32 alias
#define WLO_OFF    XBUF_BYTES
#define WLO_BYTES  (2*PP*XP*2)           // 67584
#define ADJS_OFF   (WLO_OFF + WLO_BYTES) // 135168
#define DIAG_OFF   (ADJS_OFF + 1216)
#define BIAS_OFF   (DIAG_OFF + 512)
#define LDS_BYTES  (BIAS_OFF + 512)      // 137408 -> 1 block/CU

__device__ __forceinline__ u16 f2bf(float f) {
  u32 u = __float_as_uint(f);
  u += 0x7FFFu + ((u >> 16) & 1u);   // RNE
  return (u16)(u >> 16);
}
__device__ __forceinline__ float bf2f(u16 h) {
  return __uint_as_float(((u32)h) << 16);
}
__device__ __forceinline__ s8v cmb(s4v a, s4v b) {
  s8v r;
  r[0]=a[0]; r[1]=a[1]; r[2]=a[2]; r[3]=a[3];
  r[4]=b[0]; r[5]=b[1]; r[6]=b[2]; r[7]=b[3];
  return r;
}
__device__ __forceinline__ float wred(float v) {
  #pragma unroll
  for (int m = 32; m >= 1; m >>= 1) v += __shfl_xor(v, m, 64);
  return v;
}

__global__ void __launch_bounds__(NT, 2)
gconv_fused(const float* __restrict__ x, const float* __restrict__ x0,
            const float* __restrict__ adj, const float* __restrict__ W0,
            const float* __restrict__ W1, const float* __restrict__ bvec,
            const float* __restrict__ gamma, const float* __restrict__ beta,
            float* __restrict__ out, int totRows)
{
  extern __shared__ char smem[];
  u16*   xh    = (u16*)smem;                   // [PP][XP]
  u16*   xl    = xh + PP*XP;
  float* h1    = (float*)smem;                 // alias, [PP][XP] f32
  float* wf32  = (float*)smem;                 // alias, flat [16384] f32
  u16*   wlo   = (u16*)(smem + WLO_OFF);       // [2][PP][XP] (n-major, k-pitched)
  float* adjs  = (float*)(smem + ADJS_OFF);    // 0.8*adj, diag zeroed
  float* diag8 = (float*)(smem + DIAG_OFF);
  float* biasl = (float*)(smem + BIAS_OFF);

  const int tid  = threadIdx.x;
  const int lane = tid & 63;
  const int wid  = tid >> 6;        // 0..7
  const int wm   = wid >> 2;        // 0..1  (M half)
  const int wn   = wid & 3;         // 0..3  (N tile)
  const int g    = lane >> 5;
  const int nl   = lane & 31;
  const int ccol = wn*32 + nl;
  const int grow0 = blockIdx.x * ROWS;

  // ---- W prep: f32 bounce via LDS; whi -> regs, wlo -> LDS (resident all layers)
  s8v whi[2][8];
  #pragma unroll
  for (int w01 = 0; w01 < 2; ++w01) {
    const float* Wp = w01 ? W1 : W0;
    if (w01) __syncthreads();
    #pragma unroll
    for (int i = 0; i < 32; ++i) wf32[tid + i*NT] = Wp[tid + i*NT];
    __syncthreads();
    #pragma unroll
    for (int ks = 0; ks < 8; ++ks) {
      s8v v;
      #pragma unroll
      for (int e = 0; e < 8; ++e)
        v[e] = (short)f2bf(wf32[(ks*16 + 8*g + e)*CC + ccol]);
      whi[w01][ks] = v;
    }
    #pragma unroll
    for (int i = 0; i < 32; ++i) {
      int el = tid + i*NT;
      int k = el >> 7, n = el & 127;
      float v = wf32[el];
      u16 h = f2bf(v);
      wlo[(w01*PP + n)*XP + k] = f2bf(v - bf2f(h));
    }
  }
  __syncthreads();   // wf32 (xbuf) free

  // ---- x0 -> 16 packed-bf16 regs (accumulator layout), read once ----
  u32 x0p[2][8];
  #pragma unroll
  for (int mt = 0; mt < 2; ++mt)
    #pragma unroll
    for (int qp = 0; qp < 8; ++qp) {
      u32 pk = 0;
      #pragma unroll
      for (int h = 0; h < 2; ++h) {
        int q = qp*2 + h;
        int row = wm*64 + mt*32 + (q&3) + 8*(q>>2) + 4*g;
        int grow = grow0 + row;
        u16 bits = 0;
        if (row < ROWS && grow < totRows)
          bits = f2bf(x0[(size_t)grow*CC + ccol]);
        pk |= ((u32)bits) << (16*h);
      }
      x0p[mt][qp] = pk;
    }

  // ---- x -> xh/xl (float4), pad rows zero
  #pragma unroll
  for (int i = 0; i < 8; ++i) {
    int el4 = tid + i*NT;            // 4096 float4
    int r = el4 >> 5, c4 = (el4 & 31) << 2;
    f4v v; v[0]=0.f; v[1]=0.f; v[2]=0.f; v[3]=0.f;
    if (r < ROWS && (grow0 + r) < totRows)
      v = *(const f4v*)&x[(size_t)(grow0 + r)*CC + c4];
    s4v sh, sl;
    #pragma unroll
    for (int e = 0; e < 4; ++e) {
      u16 hh = f2bf(v[e]);
      sh[e] = (short)hh;
      sl[e] = (short)f2bf(v[e] - bf2f(hh));
    }
    *(s4v*)&xh[r*XP + c4] = sh;
    *(s4v*)&xl[r*XP + c4] = sl;
  }
  if (tid < JJ*JJ) {
    int j = tid / JJ, k = tid - j*JJ;
    adjs[tid] = (j == k) ? 0.f : 0.8f * adj[tid];
  }
  if (tid < PP) {
    int j = tid % JJ;
    diag8[tid] = (tid < ROWS) ? 0.8f * adj[j*JJ + j] : 0.f;
    biasl[tid] = bvec[tid];
  }
  __syncthreads();

  // ================= layer loop =================
  #pragma unroll 1
  for (int layer = 0; layer < NLAYERS; ++layer) {
    f16v acc0[2], acc1[2];
    #pragma unroll
    for (int mt = 0; mt < 2; ++mt)
      #pragma unroll
      for (int i = 0; i < 16; ++i) { acc0[mt][i] = 0.f; acc1[mt][i] = 0.f; }

    // ---- GEMM: LDS + regs only; sched_barrier bounds liveness per K-step
    #pragma unroll
    for (int ks = 0; ks < 8; ++ks) {
      const int bb0 = ccol*XP + ks*16 + 8*g;
      s8v bl0 = cmb(*(const s4v*)&wlo[bb0], *(const s4v*)&wlo[bb0+4]);
      s8v bl1 = cmb(*(const s4v*)&wlo[PP*XP + bb0], *(const s4v*)&wlo[PP*XP + bb0+4]);
      #pragma unroll
      for (int mt = 0; mt < 2; ++mt) {
        const int xb = (wm*64 + mt*32 + nl)*XP + ks*16 + 8*g;
        s8v ah = cmb(*(const s4v*)&xh[xb], *(const s4v*)&xh[xb+4]);
        s8v al = cmb(*(const s4v*)&xl[xb], *(const s4v*)&xl[xb+4]);
        acc0[mt] = __builtin_amdgcn_mfma_f32_32x32x16_bf16(ah, whi[0][ks], acc0[mt], 0, 0, 0);
        acc0[mt] = __builtin_amdgcn_mfma_f32_32x32x16_bf16(al, whi[0][ks], acc0[mt], 0, 0, 0);
        acc0[mt] = __builtin_amdgcn_mfma_f32_32x32x16_bf16(ah, bl0,        acc0[mt], 0, 0, 0);
        acc1[mt] = __builtin_amdgcn_mfma_f32_32x32x16_bf16(ah, whi[1][ks], acc1[mt], 0, 0, 0);
        acc1[mt] = __builtin_amdgcn_mfma_f32_32x32x16_bf16(al, whi[1][ks], acc1[mt], 0, 0, 0);
        acc1[mt] = __builtin_amdgcn_mfma_f32_32x32x16_bf16(ah, bl1,        acc1[mt], 0, 0, 0);
      }
      __builtin_amdgcn_sched_barrier(0);   // cap fragment liveness at one K-step
    }
    __syncthreads();               // xh/xl reads done (h1 aliases them)

    // ---- epilogue: acc1 (X@W1) -> h1
    #pragma unroll
    for (int mt = 0; mt < 2; ++mt)
      #pragma unroll
      for (int q = 0; q < 16; ++q) {
        int row = wm*64 + mt*32 + (q&3) + 8*(q>>2) + 4*g;
        h1[row*XP + ccol] = acc1[mt][q];
      }
    __syncthreads();

    // ---- joint mix in place (wave wid = batch elem)
    if (wid < BB) {
      const int rb = wid * JJ;
      f2v h[JJ];
      #pragma unroll
      for (int k = 0; k < JJ; ++k)
        h[k] = *(const f2v*)&h1[(rb+k)*XP + 2*lane];
      #pragma unroll 1
      for (int j = 0; j < JJ; ++j) {
        f2v m; m.x = 0.f; m.y = 0.f;
        #pragma unroll
        for (int k = 0; k < JJ; ++k) {
          float a = adjs[j*JJ + k];
          m.x += a * h[k].x; m.y += a * h[k].y;
        }
        *(f2v*)&h1[(rb+j)*XP + 2*lane] = m;
      }
    }
    __syncthreads();

    // ---- combine A: gather into regs (x0 from registers)
    float tmp[2][16];
    #pragma unroll
    for (int mt = 0; mt < 2; ++mt)
      #pragma unroll
      for (int q = 0; q < 16; ++q) {
        int row = wm*64 + mt*32 + (q&3) + 8*(q>>2) + 4*g;
        float x0v = bf2f((u16)(x0p[mt][q>>1] >> (16*(q&1))));
        tmp[mt][q] = 0.2f*x0v + diag8[row]*acc0[mt][q] + h1[row*XP + ccol] + biasl[ccol];
      }
    __syncthreads();               // h1 reads done before xh/xl overwrite

    // ---- combine B: write new x split
    #pragma unroll
    for (int mt = 0; mt < 2; ++mt)
      #pragma unroll
      for (int q = 0; q < 16; ++q) {
        int row = wm*64 + mt*32 + (q&3) + 8*(q>>2) + 4*g;
        u16 hh = f2bf(tmp[mt][q]);
        xh[row*XP + ccol] = hh;
        xl[row*XP + ccol] = f2bf(tmp[mt][q] - bf2f(hh));
      }
    __syncthreads();
  }

  // ---- LayerNorm + store
  float ga = gamma[lane], g2 = gamma[64+lane];
  float ba = beta[lane],  b2 = beta[64+lane];
  #pragma unroll 1
  for (int i = 0; i < 16; ++i) {
    int r = wid + 8*i;             // wave-uniform
    if (r >= ROWS) continue;
    int grow = grow0 + r;
    if (grow >= totRows) continue;
    int xb = r*XP;
    float xa = bf2f(xh[xb+lane])    + bf2f(xl[xb+lane]);
    float xc = bf2f(xh[xb+64+lane]) + bf2f(xl[xb+64+lane]);
    float mu = wred(xa + xc) * (1.f/128.f);
    float da = xa - mu, dc = xc - mu;
    float vs = wred(da*da + dc*dc) * (1.f/128.f);
    float rs = rsqrtf(vs + 1e-10f);
    size_t ob = (size_t)grow*CC;
    out[ob + lane]      = da*rs*ga + ba;
    out[ob + 64 + lane] = dc*rs*g2 + b2;
  }
}

extern "C" void kernel_launch(void* const* d_in, const int* in_sizes, int n_in,
                              void* d_out, int out_size, void* d_ws, size_t ws_size,
                              hipStream_t stream) {
  const float* x   = (const float*)d_in[0];
  const float* x0  = (const float*)d_in[1];
  const float* adj = (const float*)d_in[2];
  const float* W0  = (const float*)d_in[3];
  const float* W1  = (const float*)d_in[4];
  const float* bv  = (const float*)d_in[5];
  const float* ga  = (const float*)d_in[6];
  const float* be  = (const float*)d_in[7];
  int totRows = in_sizes[0] / CC;
  int nBatch  = totRows / JJ;
  int grid    = (nBatch + BB - 1) / BB;
  hipFuncSetAttribute((const void*)gconv_fused,
                      hipFuncAttributeMaxDynamicSharedMemorySize, LDS_BYTES);
  gconv_fused<<<dim3(grid), dim3(NT), LDS_BYTES, stream>>>(
      x, x0, adj, W0, W1, bv, ga, be, (float*)d_out, totRows);
}